// Round 28
// baseline (444.719 us; speedup 1.0000x reference)
//
#include <hip/hip_runtime.h>
#include <math.h>

#define TILE 128
#define BK   64
#define NT   256

typedef __attribute__((ext_vector_type(8))) short bf16x8;
typedef __attribute__((ext_vector_type(4))) float f32x4;

typedef const __attribute__((address_space(1))) void* gvp;
typedef __attribute__((address_space(3))) void* lvp;

__device__ __forceinline__ float bf2f(unsigned short u) {
  union { unsigned int i; float f; } v; v.i = ((unsigned int)u) << 16; return v.f;
}
__device__ __forceinline__ unsigned short f2bf(float f) {
  union { float ff; unsigned int i; } v; v.ff = f;
  return (unsigned short)((v.i + 0x7fffu + ((v.i >> 16) & 1u)) >> 16);
}

// bijective XCD-chunk swizzle (m204). Measured wins: PV FETCH 260->55MB (R7),
// projall FETCH 229->51MB (R14/R26).
__device__ __forceinline__ int xcd_swz(int h, int nwg) {
  int q = nwg >> 3, r = nwg & 7;
  int xcd = h & 7, pos = h >> 3;
  return (xcd < r ? xcd * (q + 1) : r * (q + 1) + (xcd - r) * q) + pos;
}

struct GemmSrc { const unsigned short* A; int lda; const unsigned short* B; int ldb; int nk; };

// Stage a 128x64 bf16 tile into LDS (256-thread form). T2 swizzle, rule #21
// form (R9 verified: BANK_CONFLICT 1.9e7 -> 0, bit-identical): LDS dest stays
// LINEAR (global_load_lds requirement); SOURCE k-chunk is inverse-swizzled, so
// LDS slot (row, kc) holds global chunk kc^(row&7). 4 VMEM ops per thread.
__device__ __forceinline__ void stage_tile(const unsigned short* g, int ld, int r0, int k0,
                                           short* lds, int tid) {
#pragma unroll
  for (int i = 0; i < 4; ++i) {
    int cid = i * NT + tid;
    int row = cid >> 3, kc = cid & 7;
    int kcs = kc ^ (row & 7);              // T2 source swizzle (involution)
    const unsigned short* src = g + (size_t)(r0 + row) * ld + (k0 + kcs * 8);
    __builtin_amdgcn_global_load_lds((gvp)src, (lvp)(lds + cid * 8), 16, 0, 0);
  }
}

// 512-thread cooperative form: identical layout, 2 chunks/thread (R26/R27/R28:
// used for the block-shared operand tile in k_projall, k_scores, k_final).
__device__ __forceinline__ void stage_tile512(const unsigned short* g, int ld, int r0, int k0,
                                              short* lds, int tid) {
#pragma unroll
  for (int i = 0; i < 2; ++i) {
    int cid = i * 512 + tid;
    int row = cid >> 3, kc = cid & 7;
    int kcs = kc ^ (row & 7);              // T2 source swizzle (involution)
    const unsigned short* src = g + (size_t)(r0 + row) * ld + (k0 + kcs * 8);
    __builtin_amdgcn_global_load_lds((gvp)src, (lvp)(lds + cid * 8), 16, 0, 0);
  }
}

// Fragment reads apply the matching XOR: chunk (kk*4+lk) of row r lives at
// LDS chunk (kk*4+lk)^(r&7). Conflict-free (R9 measured).
__device__ __forceinline__ void compute_tile(const short* As, const short* Bs,
                                             f32x4 acc[4][4], int lr, int lk, int wm, int wn) {
#pragma unroll
  for (int kk = 0; kk < 2; ++kk) {
    bf16x8 a[4], b[4];
#pragma unroll
    for (int i = 0; i < 4; ++i) {
      int ra = wm * 64 + i * 16 + lr;
      int rb = wn * 64 + i * 16 + lr;
      int ca = ((kk * 4 + lk) ^ (ra & 7)) * 8;
      int cb = ((kk * 4 + lk) ^ (rb & 7)) * 8;
      a[i] = *(const bf16x8*)(As + ra * BK + ca);
      b[i] = *(const bf16x8*)(Bs + rb * BK + cb);
    }
#pragma unroll
    for (int i = 0; i < 4; ++i)
#pragma unroll
      for (int j = 0; j < 4; ++j)
        acc[i][j] = __builtin_amdgcn_mfma_f32_16x16x32_bf16(a[i], b[j], acc[i][j], 0, 0, 0);
  }
}

// single-buffered K-loop: 2 barriers/step. Best when the CU holds multiple
// independent staging streams (R23 pv 900 TF, R24 scores ~1050 TF).
template<int NS>
__device__ __forceinline__ void gemm_accum(const GemmSrc* s, f32x4 acc[4][4],
                                           short* As, short* Bs, int tid, int r0, int c0) {
  int lane = tid & 63, w = tid >> 6;
  int lr = lane & 15, lk = lane >> 4;
  int wm = w >> 1, wn = w & 1;
#pragma unroll
  for (int si = 0; si < NS; ++si) {
    int nk = s[si].nk;
    for (int kt = 0; kt < nk; ++kt) {
      __syncthreads();
      stage_tile(s[si].A, s[si].lda, r0, kt * BK, As, tid);
      stage_tile(s[si].B, s[si].ldb, c0, kt * BK, Bs, tid);
      __syncthreads();
      compute_tile(As, Bs, acc, lr, lk, wm, wn);
    }
  }
}

// C/D layout for mfma_f32_16x16x32_bf16: col = lane&15, row = (lane>>4)*4 + reg
template<bool OUT_BF16, bool BIAS_N, bool BIAS_M>
__device__ __forceinline__ void gemm_epilogue(f32x4 acc[4][4], void* C, int ldc,
                                              int r0, int c0, const float* bias,
                                              float alpha, int tid) {
  int lane = tid & 63, w = tid >> 6;
  int lr = lane & 15, lk = lane >> 4;
  int wm = w >> 1, wn = w & 1;
#pragma unroll
  for (int i = 0; i < 4; ++i) {
#pragma unroll
    for (int j = 0; j < 4; ++j) {
      int col = c0 + wn * 64 + j * 16 + lr;
      float bn = BIAS_N ? bias[col] : 0.f;
#pragma unroll
      for (int r = 0; r < 4; ++r) {
        int row = r0 + wm * 64 + i * 16 + lk * 4 + r;
        float v = acc[i][j][r] * alpha + bn;
        if (BIAS_M) v += bias[row];
        size_t idx = (size_t)row * ldc + col;
        if (OUT_BF16) ((unsigned short*)C)[idx] = f2bf(v);
        else          ((float*)C)[idx] = v;
      }
    }
  }
}

__device__ __forceinline__ void zero_acc(f32x4 acc[4][4]) {
  f32x4 z = { 0.f, 0.f, 0.f, 0.f };
#pragma unroll
  for (int i = 0; i < 4; ++i)
#pragma unroll
    for (int j = 0; j < 4; ++j) acc[i][j] = z;
}

// ---------------- kernels ----------------

struct ConvW { const float* src[7]; unsigned short* dst[7]; };

__global__ __launch_bounds__(NT) void k_convert_w(ConvW a) {
  int z = blockIdx.y;
  const float* s = a.src[z];
  unsigned short* d = a.dst[z];
  const int n = 768 * 768;
  int stride = gridDim.x * NT * 4;
  for (int i = ((int)blockIdx.x * NT + (int)threadIdx.x) * 4; i < n; i += stride) {
    float4 f = *(const float4*)(s + i);
    ushort4 o;
    o.x = f2bf(f.x); o.y = f2bf(f.y); o.z = f2bf(f.z); o.w = f2bf(f.w);
    *(ushort4*)(d + i) = o;
  }
}

// group Z slices fp32 -> bf16; also zeroes lsum (R22: folded k_zero in).
__global__ __launch_bounds__(NT) void k_convert_z(const float* zg, const float* zl,
                                                  unsigned short* dg, unsigned short* dl,
                                                  float* lsum, int nL,
                                                  long long off, int n) {
  if (blockIdx.y == 0) {
    int fid = ((int)blockIdx.x * NT + (int)threadIdx.x) * 4;
    if (fid < nL) *(float4*)(lsum + fid) = make_float4(0.f, 0.f, 0.f, 0.f);
  }
  const float* s = (blockIdx.y ? zl : zg) + off;
  unsigned short* d = blockIdx.y ? dl : dg;
  int stride = gridDim.x * NT * 4;
  for (int i = ((int)blockIdx.x * NT + (int)threadIdx.x) * 4; i < n; i += stride) {
    float4 f = *(const float4*)(s + i);
    ushort4 o;
    o.x = f2bf(f.x); o.y = f2bf(f.y); o.z = f2bf(f.z); o.w = f2bf(f.w);
    *(ushort4*)(d + i) = o;
  }
}

// Merged projections. R26: SHARED-OPERAND blocks (non-vt: z-pairs share the
// Z panel; vt: both groups share the Z col-panel). Shared tile staged ONCE by
// all 512 threads into lds[0]; per-group tile into lds[2+grp]. -25% staging.
struct ProjAllArgs {
  const unsigned short* A[6];   // z<4: Z source; z>=4: Wv
  const unsigned short* B[6];   // z<4: W;        z>=4: Z source
  const float* bias[6];
  unsigned short* dst[6];
  int SG;
};

__global__ __launch_bounds__(512) void k_projall(ProjAllArgs p) {
  __shared__ __align__(16) short lds[4][TILE * BK];   // [0]=shared, [2],[3]=per-group
  int nwg = (int)gridDim.x;                           // = 18 * RT
  int RT = p.SG / TILE;
  int l = xcd_swz((int)blockIdx.x, nwg);
  int tid = (int)threadIdx.x;
  int grp = tid >> 8, gt = tid & 255;
  int lane = gt & 63, w = gt >> 6;
  int lr = lane & 15, lk = lane >> 4, wm = w >> 1, wn = w & 1;
  f32x4 acc[4][4]; zero_acc(acc);
  int nvt = 12 * RT;                                  // non-vt pair-blocks
  if (l < nvt) {
    // non-vt: C = Z @ W^T + b. zp 0 -> (z0,z3) share Zg; zp 1 -> (z1,z2) share Zl.
    int zp = l / (6 * RT), t = l % (6 * RT);
    int r0 = (t / 6) * TILE, c0 = (t % 6) * TILE;
    int z = zp == 0 ? (grp ? 3 : 0) : (grp ? 2 : 1);
    const unsigned short* Asrc = p.A[z];              // same for both groups
    const unsigned short* Bsrc = p.B[z];              // per-group weight
    for (int kt = 0; kt < 768 / BK; ++kt) {
      __syncthreads();
      stage_tile512(Asrc, 768, r0, kt * BK, lds[0], tid);
      stage_tile(Bsrc, 768, c0, kt * BK, lds[2 + grp], gt);
      __syncthreads();
      compute_tile(lds[0], lds[2 + grp], acc, lr, lk, wm, wn);
    }
    gemm_epilogue<true, true, false>(acc, p.dst[z], 768, r0, c0, p.bias[z], 1.f, gt);
  } else {
    // vt: V^T = Wv @ Z^T + b(row). Both groups share the Z col-panel (B).
    int lv = l - nvt;                                 // [0, 6*RT)
    int z = 4 + lv / (3 * RT), t = lv % (3 * RT);
    int r0 = ((t % 3) * 2 + grp) * TILE, c0 = (t / 3) * TILE;
    const unsigned short* Asrc = p.A[z];              // per-group rows of Wv
    const unsigned short* Bsrc = p.B[z];              // shared Z panel
    for (int kt = 0; kt < 768 / BK; ++kt) {
      __syncthreads();
      stage_tile512(Bsrc, 768, c0, kt * BK, lds[0], tid);
      stage_tile(Asrc, 768, r0, kt * BK, lds[2 + grp], gt);
      __syncthreads();
      compute_tile(lds[2 + grp], lds[0], acc, lr, lk, wm, wn);
    }
    gemm_epilogue<true, false, true>(acc, p.dst[z], p.SG, r0, c0, p.bias[z], 1.f, gt);
  }
}

// E[z] = exp(Q_gi @ K_gi^T * alpha)  (NO max subtraction: S*alpha ~ N(0,0.33),
// max ~1.8, exp<=12 -- f32 overflows at 88, so max-sub is unnecessary here).
// Row sums l[z][row] via shfl-reduce + atomicAdd; k_pv divides by l, making
// E@V/l == softmax(S)@V exactly.
// R27: SHARED-Q blocks: Q staged ONCE by all 512 threads into lds[0];
// per-group K into lds[2+grp]. Es overlay: grp0 -> lds[0..1], grp1 -> lds[2..3].
__global__ __launch_bounds__(512) void k_scores(const unsigned short* Qg, const unsigned short* Kl,
                                                const unsigned short* Ql, const unsigned short* Kg,
                                                unsigned short* S, float* lsum,
                                                float alpha, int G) {
  __shared__ __align__(16) short lds[4][TILE * BK];   // [0]=Q shared; [2],[3]=per-group K
  int nwg = (int)(gridDim.x * gridDim.y * gridDim.z);
  int h = (int)blockIdx.x + (int)gridDim.x * ((int)blockIdx.y + (int)gridDim.y * (int)blockIdx.z);
  int l = xcd_swz(h, nwg);
  int xp = l & 7, y = (l >> 3) & 15, z = l >> 7;     // gridDim = (8, 16, 2G)
  int tid = (int)threadIdx.x;
  int grp = tid >> 8;    // 0 or 1
  int gt  = tid & 255;
  int x = xp * 2 + grp;
  int dir = (z >= G) ? 1 : 0, gi = z - dir * G;
  const unsigned short* Q = (dir ? Ql : Qg) + (size_t)gi * 2048 * 768;
  const unsigned short* K = (dir ? Kg : Kl) + (size_t)gi * 2048 * 768;
  unsigned short* C = S + (size_t)z * 2048 * 2048;
  float* lrow = lsum + (size_t)z * 2048;
  int r0 = y * TILE, c0 = x * TILE;
  int lane = gt & 63, w = gt >> 6;
  int lr = lane & 15, lk = lane >> 4, wm = w >> 1, wn = w & 1;
  f32x4 acc[4][4]; zero_acc(acc);
  // shared-Q K-loop: Q staged once per block, K per group; lockstep barriers
  for (int kt = 0; kt < 768 / BK; ++kt) {
    __syncthreads();
    stage_tile512(Q, 768, r0, kt * BK, lds[0], tid);
    stage_tile(K, 768, c0, kt * BK, lds[2 + grp], gt);
    __syncthreads();
    compute_tile(lds[0], lds[2 + grp], acc, lr, lk, wm, wn);
  }
  // exp + row-sum, staging E into this group's swizzled LDS region (R15 store)
  __syncthreads();                       // all groups done reading staging
  short* Es = grp ? lds[2] : lds[0];     // 32KB contiguous per group
#pragma unroll
  for (int i = 0; i < 4; ++i) {
    float rs[4] = { 0.f, 0.f, 0.f, 0.f };
#pragma unroll
    for (int j = 0; j < 4; ++j) {
      int lcol = wn * 64 + j * 16 + lr;
#pragma unroll
      for (int r = 0; r < 4; ++r) {
        int lrw = wm * 64 + i * 16 + lk * 4 + r;
        unsigned short eb = f2bf(__expf(acc[i][j][r] * alpha));
        // XOR maps the 4 rows of a wave-write to 4 distinct 16-col blocks ->
        // 64 lanes cover all 32 banks (2-way max = free, m136)
        Es[lrw * TILE + (lcol ^ ((lrw & 7) << 4))] = (short)eb;
        rs[r] += bf2f(eb);               // sum the ROUNDED value PV consumes
      }
    }
#pragma unroll
    for (int r = 0; r < 4; ++r) {
      float v = rs[r];
      v += __shfl_xor(v, 1); v += __shfl_xor(v, 2);
      v += __shfl_xor(v, 4); v += __shfl_xor(v, 8);
      if (lr == 0) atomicAdd(&lrow[r0 + wm * 64 + i * 16 + lk * 4 + r], v);
    }
  }
  __syncthreads();
  // coalesced write-back: 8 x 16B chunks/thread; 16 lanes cover one 256B row
#pragma unroll
  for (int c = 0; c < 8; ++c) {
    int id = c * 256 + gt;
    int lrw = id >> 4, cc = id & 15;     // row, 16B-chunk within row
    uint4 v = *(const uint4*)(Es + lrw * TILE + ((cc * 8) ^ ((lrw & 7) << 4)));
    *(uint4*)(C + (size_t)(r0 + lrw) * 2048 + c0 + cc * 8) = v;
  }
}

// Zf[gi] = (E0 @ Vl)/l0 + (E1 @ Vg)/l1. Split-direction block (R12):
// 512 threads = 2 groups x 4 waves; group g computes E_g @ V_g, scales by
// 1/l_g, then LDS handoff + add.
// R23: LDS 64KB (single-buffer loop per group; f32 reduction buffer OVERLAYS
// staging after a barrier). All blocks co-reside at 2/CU -> no dispatch tail.
__global__ __launch_bounds__(512) void k_pv(const unsigned short* S, const unsigned short* VlT,
                                            const unsigned short* VgT, const float* lsum,
                                            unsigned short* Zf, int G, int SG) {
  __shared__ __align__(16) short lds[4][TILE * BK];   // 4 x 16KB = 64KB
  int nwg = (int)(gridDim.x * gridDim.y * gridDim.z);
  int h = (int)blockIdx.x + (int)gridDim.x * ((int)blockIdx.y + (int)gridDim.y * (int)blockIdx.z);
  int l = xcd_swz(h, nwg);
  int x = l % 6, t2 = l / 6;
  int y = t2 & 15, z = t2 >> 4;        // z in [0,G)
  int r0 = y * TILE, c0 = x * TILE;
  int grp = (int)threadIdx.x >> 8;     // 0 or 1
  int gt  = (int)threadIdx.x & 255;
  f32x4 acc[4][4]; zero_acc(acc);
  GemmSrc s;
  if (grp == 0) s = { S + (size_t)z * 2048 * 2048,       2048, VlT + (size_t)z * 2048, SG, 2048 / BK };
  else          s = { S + (size_t)(G + z) * 2048 * 2048, 2048, VgT + (size_t)z * 2048, SG, 2048 / BK };
  // lockstep: both groups run identical 32-step loops -> barrier counts match
  gemm_accum<1>(&s, acc, lds[grp * 2], lds[grp * 2 + 1], gt, r0, c0);
  int lane = gt & 63, w = gt >> 6;
  int lr = lane & 15, lk = lane >> 4, wm = w >> 1, wn = w & 1;
  // scale this group's partial by its own softmax denominator
  const float* lb = lsum + (size_t)(grp ? (G + z) : z) * 2048;
  float linv[4][4];
#pragma unroll
  for (int i = 0; i < 4; ++i)
#pragma unroll
    for (int r = 0; r < 4; ++r)
      linv[i][r] = 1.0f / lb[r0 + wm * 64 + i * 16 + lk * 4 + r];
#pragma unroll
  for (int i = 0; i < 4; ++i)
#pragma unroll
    for (int j = 0; j < 4; ++j)
#pragma unroll
      for (int r = 0; r < 4; ++r)
        acc[i][j][r] *= linv[i][r];
  float* red = (float*)lds;            // overlays staging (64KB = 128x128 f32)
  __syncthreads();                     // all reads of staging LDS complete
  if (grp == 1) {
#pragma unroll
    for (int i = 0; i < 4; ++i)
#pragma unroll
      for (int j = 0; j < 4; ++j)
#pragma unroll
        for (int r = 0; r < 4; ++r) {
          int row = wm * 64 + i * 16 + lk * 4 + r;
          int col = wn * 64 + j * 16 + lr;
          red[row * 128 + col] = acc[i][j][r];
        }
  }
  __syncthreads();
  if (grp == 0) {
#pragma unroll
    for (int i = 0; i < 4; ++i)
#pragma unroll
      for (int j = 0; j < 4; ++j)
#pragma unroll
        for (int r = 0; r < 4; ++r) {
          int row = wm * 64 + i * 16 + lk * 4 + r;
          int col = wn * 64 + j * 16 + lr;
          acc[i][j][r] += red[row * 128 + col];
        }
    gemm_epilogue<true, false, false>(acc, Zf + (size_t)z * 2048 * 768, 768, r0, c0,
                                      nullptr, 1.f, gt);
  }
}

// out_grp = Zf_grp @ Wf^T + bf (fp32 out) : M=SG, N=768, K=768.
// R28: SHARED-A 512-thread blocks (5th application; mirrors projall non-vt):
// column-tile pairs share the Zf row panel -- staged ONCE by all 512 threads
// into lds[0]; per-group Wf tile into lds[2+grp]. Grid 3*RT blocks, all
// co-resident in one dispatch round (vs 384-block/1.5-round makespan).
__global__ __launch_bounds__(512) void k_final(const unsigned short* Zf, const unsigned short* Wf,
                                               const float* bias, float* out) {
  __shared__ __align__(16) short lds[4][TILE * BK];   // [0]=shared Zf; [2],[3]=per-group Wf
  int nwg = (int)gridDim.x;                           // = 3 * RT
  int l = xcd_swz((int)blockIdx.x, nwg);
  int tid = (int)threadIdx.x;
  int grp = tid >> 8, gt = tid & 255;
  int r0 = (l / 3) * TILE;
  int c0 = ((l % 3) * 2 + grp) * TILE;
  int lane = gt & 63, w = gt >> 6;
  int lr = lane & 15, lk = lane >> 4, wm = w >> 1, wn = w & 1;
  f32x4 acc[4][4]; zero_acc(acc);
  for (int kt = 0; kt < 768 / BK; ++kt) {
    __syncthreads();
    stage_tile512(Zf, 768, r0, kt * BK, lds[0], tid);
    stage_tile(Wf, 768, c0, kt * BK, lds[2 + grp], gt);
    __syncthreads();
    compute_tile(lds[0], lds[2 + grp], acc, lr, lk, wm, wn);
  }
  gemm_epilogue<false, true, false>(acc, out, 768, r0, c0, bias, 1.f, gt);
}

// ---------------- launch ----------------

extern "C" void kernel_launch(void* const* d_in, const int* in_sizes, int n_in,
                              void* d_out, int out_size, void* d_ws, size_t ws_size,
                              hipStream_t stream) {
  const int B = 8, S = 2048, D = 768;

  const float* Zg  = (const float*)d_in[0];
  const float* Zl  = (const float*)d_in[1];
  const float* bqg = (const float*)d_in[3];
  const float* bkl = (const float*)d_in[5];
  const float* bvl = (const float*)d_in[7];
  const float* bql = (const float*)d_in[9];
  const float* bkg = (const float*)d_in[11];
  const float* bvg = (const float*)d_in[13];
  const float* bf  = (const float*)d_in[15];

  // need(G) = 7 weights + 6 group bufs + lsum + max(Zbf pair, 2G score slices)
  // + 1MB. G=8: 295MB, G=4: 152, G=2: 80.6. R18 ledger implies G=4 engages.
  auto needG = [&](int G) -> size_t {
    size_t zrow = (size_t)G * S * D * 2;
    size_t sb = (size_t)2 * G * S * S * 2;
    size_t zbf = 2 * zrow;
    return 7 * ((size_t)D * D * 2) + 6 * zrow + (size_t)2 * G * S * 4
         + (sb > zbf ? sb : zbf) + (1u << 20);
  };
  int G = 1;
  if      (ws_size >= needG(8)) G = 8;
  else if (ws_size >= needG(4)) G = 4;
  else if (ws_size >= needG(2)) G = 2;
  const int SG = G * S;

  char* w = (char*)d_ws;
  size_t off = 0;
  auto alloc = [&](size_t bytes) -> char* {
    char* p = w + off; off += (bytes + 255) & ~(size_t)255; return p;
  };
  const size_t ZROW = (size_t)SG * D * 2;
  unsigned short* Wbf[7];
  for (int i = 0; i < 7; ++i) Wbf[i] = (unsigned short*)alloc((size_t)D * D * 2);
  unsigned short* QgZf  = (unsigned short*)alloc(ZROW);  // Qg, then reused as Zf
  unsigned short* Kl    = (unsigned short*)alloc(ZROW);
  unsigned short* Ql    = (unsigned short*)alloc(ZROW);
  unsigned short* Kg    = (unsigned short*)alloc(ZROW);
  unsigned short* VlT   = (unsigned short*)alloc(ZROW);  // [768][SG]
  unsigned short* VgT   = (unsigned short*)alloc(ZROW);  // [768][SG]
  float* lsum = (float*)alloc((size_t)2 * G * S * 4);    // [2G][2048] row sums
  // Overlay: Zg_bf/Zl_bf (convert->projall) share space with Sb (scores->pv)
  size_t ov = off;
  unsigned short* Zg_bf = (unsigned short*)alloc(ZROW);
  unsigned short* Zl_bf = (unsigned short*)alloc(ZROW);
  unsigned short* Sb    = (unsigned short*)(w + ov);

  // weights fp32 -> bf16 (once). Order: Wqg Wkl Wvl Wql Wkg Wvg Wf.
  ConvW cw;
  cw.src[0] = (const float*)d_in[2];  cw.src[1] = (const float*)d_in[4];
  cw.src[2] = (const float*)d_in[6];  cw.src[3] = (const float*)d_in[8];
  cw.src[4] = (const float*)d_in[10]; cw.src[5] = (const float*)d_in[12];
  cw.src[6] = (const float*)d_in[14];
  for (int i = 0; i < 7; ++i) cw.dst[i] = Wbf[i];
  k_convert_w<<<dim3(576, 7), NT, 0, stream>>>(cw);

  // merged projections (4 proj + 2 projVT)
  ProjAllArgs pj;
  pj.A[0] = Zg_bf;  pj.B[0] = Wbf[0]; pj.bias[0] = bqg; pj.dst[0] = QgZf;
  pj.A[1] = Zl_bf;  pj.B[1] = Wbf[1]; pj.bias[1] = bkl; pj.dst[1] = Kl;
  pj.A[2] = Zl_bf;  pj.B[2] = Wbf[3]; pj.bias[2] = bql; pj.dst[2] = Ql;
  pj.A[3] = Zg_bf;  pj.B[3] = Wbf[4]; pj.bias[3] = bkg; pj.dst[3] = Kg;
  pj.A[4] = Wbf[2]; pj.B[4] = Zl_bf;  pj.bias[4] = bvl; pj.dst[4] = VlT;
  pj.A[5] = Wbf[5]; pj.B[5] = Zg_bf;  pj.bias[5] = bvg; pj.dst[5] = VgT;
  pj.SG = SG;

  float alpha = 1.0f / sqrtf(768.0f);
  const int nZ = SG * D;
  const int nL = 2 * G * S;   // lsum element count
  const int RT = SG / TILE;

  for (int b0 = 0; b0 < B; b0 += G) {
    k_convert_z<<<dim3(1024, 2), NT, 0, stream>>>(Zg, Zl, Zg_bf, Zl_bf, lsum, nL,
                                                  (long long)b0 * S * D, nZ);
    k_projall<<<dim3(18 * RT), 512, 0, stream>>>(pj);
    k_scores<<<dim3(8, 16, 2 * G), 512, 0, stream>>>(QgZf, Kl, Ql, Kg, Sb, lsum, alpha, G);
    k_pv<<<dim3(6, 16, G), 512, 0, stream>>>(Sb, VlT, VgT, lsum, QgZf, G, SG);
    k_final<<<dim3(3 * RT), 512, 0, stream>>>(QgZf, Wbf[6], bf,
                                              (float*)d_out + (size_t)b0 * S * D);
  }
}

// Round 29
// 432.999 us; speedup vs baseline: 1.0271x; 1.0271x over previous
//
#include <hip/hip_runtime.h>
#include <math.h>

#define TILE 128
#define BK   64
#define NT   256

typedef __attribute__((ext_vector_type(8))) short bf16x8;
typedef __attribute__((ext_vector_type(4))) float f32x4;

typedef const __attribute__((address_space(1))) void* gvp;
typedef __attribute__((address_space(3))) void* lvp;

__device__ __forceinline__ float bf2f(unsigned short u) {
  union { unsigned int i; float f; } v; v.i = ((unsigned int)u) << 16; return v.f;
}
__device__ __forceinline__ unsigned short f2bf(float f) {
  union { float ff; unsigned int i; } v; v.ff = f;
  return (unsigned short)((v.i + 0x7fffu + ((v.i >> 16) & 1u)) >> 16);
}

// bijective XCD-chunk swizzle (m204). Measured wins: PV FETCH 260->55MB (R7),
// projall FETCH 229->51MB (R14/R26).
__device__ __forceinline__ int xcd_swz(int h, int nwg) {
  int q = nwg >> 3, r = nwg & 7;
  int xcd = h & 7, pos = h >> 3;
  return (xcd < r ? xcd * (q + 1) : r * (q + 1) + (xcd - r) * q) + pos;
}

struct GemmSrc { const unsigned short* A; int lda; const unsigned short* B; int ldb; int nk; };

// Stage a 128x64 bf16 tile into LDS (256-thread form). T2 swizzle, rule #21
// form (R9 verified: BANK_CONFLICT 1.9e7 -> 0, bit-identical): LDS dest stays
// LINEAR (global_load_lds requirement); SOURCE k-chunk is inverse-swizzled, so
// LDS slot (row, kc) holds global chunk kc^(row&7). 4 VMEM ops per thread.
__device__ __forceinline__ void stage_tile(const unsigned short* g, int ld, int r0, int k0,
                                           short* lds, int tid) {
#pragma unroll
  for (int i = 0; i < 4; ++i) {
    int cid = i * NT + tid;
    int row = cid >> 3, kc = cid & 7;
    int kcs = kc ^ (row & 7);              // T2 source swizzle (involution)
    const unsigned short* src = g + (size_t)(r0 + row) * ld + (k0 + kcs * 8);
    __builtin_amdgcn_global_load_lds((gvp)src, (lvp)(lds + cid * 8), 16, 0, 0);
  }
}

// 512-thread cooperative form: identical layout, 2 chunks/thread (R26/R27:
// used for the block-shared operand tile in k_projall and k_scores).
__device__ __forceinline__ void stage_tile512(const unsigned short* g, int ld, int r0, int k0,
                                              short* lds, int tid) {
#pragma unroll
  for (int i = 0; i < 2; ++i) {
    int cid = i * 512 + tid;
    int row = cid >> 3, kc = cid & 7;
    int kcs = kc ^ (row & 7);              // T2 source swizzle (involution)
    const unsigned short* src = g + (size_t)(r0 + row) * ld + (k0 + kcs * 8);
    __builtin_amdgcn_global_load_lds((gvp)src, (lvp)(lds + cid * 8), 16, 0, 0);
  }
}

// Fragment reads apply the matching XOR: chunk (kk*4+lk) of row r lives at
// LDS chunk (kk*4+lk)^(r&7). Conflict-free (R9 measured).
__device__ __forceinline__ void compute_tile(const short* As, const short* Bs,
                                             f32x4 acc[4][4], int lr, int lk, int wm, int wn) {
#pragma unroll
  for (int kk = 0; kk < 2; ++kk) {
    bf16x8 a[4], b[4];
#pragma unroll
    for (int i = 0; i < 4; ++i) {
      int ra = wm * 64 + i * 16 + lr;
      int rb = wn * 64 + i * 16 + lr;
      int ca = ((kk * 4 + lk) ^ (ra & 7)) * 8;
      int cb = ((kk * 4 + lk) ^ (rb & 7)) * 8;
      a[i] = *(const bf16x8*)(As + ra * BK + ca);
      b[i] = *(const bf16x8*)(Bs + rb * BK + cb);
    }
#pragma unroll
    for (int i = 0; i < 4; ++i)
#pragma unroll
      for (int j = 0; j < 4; ++j)
        acc[i][j] = __builtin_amdgcn_mfma_f32_16x16x32_bf16(a[i], b[j], acc[i][j], 0, 0, 0);
  }
}

// single-buffered K-loop: 2 barriers/step. Best when the CU holds multiple
// independent staging streams (R23 pv 900 TF, R24 scores ~1050 TF).
template<int NS>
__device__ __forceinline__ void gemm_accum(const GemmSrc* s, f32x4 acc[4][4],
                                           short* As, short* Bs, int tid, int r0, int c0) {
  int lane = tid & 63, w = tid >> 6;
  int lr = lane & 15, lk = lane >> 4;
  int wm = w >> 1, wn = w & 1;
#pragma unroll
  for (int si = 0; si < NS; ++si) {
    int nk = s[si].nk;
    for (int kt = 0; kt < nk; ++kt) {
      __syncthreads();
      stage_tile(s[si].A, s[si].lda, r0, kt * BK, As, tid);
      stage_tile(s[si].B, s[si].ldb, c0, kt * BK, Bs, tid);
      __syncthreads();
      compute_tile(As, Bs, acc, lr, lk, wm, wn);
    }
  }
}

// paired-step quad-buffer K-loop (R16/R18-proven on 256-thread kernels).
__device__ __forceinline__ void gemm_accum_pair(const unsigned short* A, int lda,
                                                const unsigned short* B, int ldb, int nk,
                                                f32x4 acc[4][4],
                                                short* A0, short* B0, short* A1, short* B1,
                                                int tid, int r0, int c0) {
  int lane = tid & 63, w = tid >> 6;
  int lr = lane & 15, lk = lane >> 4;
  int wm = w >> 1, wn = w & 1;
  for (int kt = 0; kt < nk / 2; ++kt) {
    __syncthreads();
    stage_tile(A, lda, r0, (2 * kt) * BK,     A0, tid);
    stage_tile(B, ldb, c0, (2 * kt) * BK,     B0, tid);
    stage_tile(A, lda, r0, (2 * kt + 1) * BK, A1, tid);
    stage_tile(B, ldb, c0, (2 * kt + 1) * BK, B1, tid);
    __syncthreads();
    compute_tile(A0, B0, acc, lr, lk, wm, wn);
    compute_tile(A1, B1, acc, lr, lk, wm, wn);
  }
}

// C/D layout for mfma_f32_16x16x32_bf16: col = lane&15, row = (lane>>4)*4 + reg
template<bool OUT_BF16, bool BIAS_N, bool BIAS_M>
__device__ __forceinline__ void gemm_epilogue(f32x4 acc[4][4], void* C, int ldc,
                                              int r0, int c0, const float* bias,
                                              float alpha, int tid) {
  int lane = tid & 63, w = tid >> 6;
  int lr = lane & 15, lk = lane >> 4;
  int wm = w >> 1, wn = w & 1;
#pragma unroll
  for (int i = 0; i < 4; ++i) {
#pragma unroll
    for (int j = 0; j < 4; ++j) {
      int col = c0 + wn * 64 + j * 16 + lr;
      float bn = BIAS_N ? bias[col] : 0.f;
#pragma unroll
      for (int r = 0; r < 4; ++r) {
        int row = r0 + wm * 64 + i * 16 + lk * 4 + r;
        float v = acc[i][j][r] * alpha + bn;
        if (BIAS_M) v += bias[row];
        size_t idx = (size_t)row * ldc + col;
        if (OUT_BF16) ((unsigned short*)C)[idx] = f2bf(v);
        else          ((float*)C)[idx] = v;
      }
    }
  }
}

__device__ __forceinline__ void zero_acc(f32x4 acc[4][4]) {
  f32x4 z = { 0.f, 0.f, 0.f, 0.f };
#pragma unroll
  for (int i = 0; i < 4; ++i)
#pragma unroll
    for (int j = 0; j < 4; ++j) acc[i][j] = z;
}

// ---------------- kernels ----------------

struct ConvW { const float* src[7]; unsigned short* dst[7]; };

__global__ __launch_bounds__(NT) void k_convert_w(ConvW a) {
  int z = blockIdx.y;
  const float* s = a.src[z];
  unsigned short* d = a.dst[z];
  const int n = 768 * 768;
  int stride = gridDim.x * NT * 4;
  for (int i = ((int)blockIdx.x * NT + (int)threadIdx.x) * 4; i < n; i += stride) {
    float4 f = *(const float4*)(s + i);
    ushort4 o;
    o.x = f2bf(f.x); o.y = f2bf(f.y); o.z = f2bf(f.z); o.w = f2bf(f.w);
    *(ushort4*)(d + i) = o;
  }
}

// group Z slices fp32 -> bf16; also zeroes lsum (R22: folded k_zero in).
__global__ __launch_bounds__(NT) void k_convert_z(const float* zg, const float* zl,
                                                  unsigned short* dg, unsigned short* dl,
                                                  float* lsum, int nL,
                                                  long long off, int n) {
  if (blockIdx.y == 0) {
    int fid = ((int)blockIdx.x * NT + (int)threadIdx.x) * 4;
    if (fid < nL) *(float4*)(lsum + fid) = make_float4(0.f, 0.f, 0.f, 0.f);
  }
  const float* s = (blockIdx.y ? zl : zg) + off;
  unsigned short* d = blockIdx.y ? dl : dg;
  int stride = gridDim.x * NT * 4;
  for (int i = ((int)blockIdx.x * NT + (int)threadIdx.x) * 4; i < n; i += stride) {
    float4 f = *(const float4*)(s + i);
    ushort4 o;
    o.x = f2bf(f.x); o.y = f2bf(f.y); o.z = f2bf(f.z); o.w = f2bf(f.w);
    *(ushort4*)(d + i) = o;
  }
}

// Merged projections. R26: SHARED-OPERAND blocks (non-vt: z-pairs share the
// Z panel; vt: both groups share the Z col-panel). Shared tile staged ONCE by
// all 512 threads into lds[0]; per-group tile into lds[2+grp]. -25% staging.
struct ProjAllArgs {
  const unsigned short* A[6];   // z<4: Z source; z>=4: Wv
  const unsigned short* B[6];   // z<4: W;        z>=4: Z source
  const float* bias[6];
  unsigned short* dst[6];
  int SG;
};

__global__ __launch_bounds__(512) void k_projall(ProjAllArgs p) {
  __shared__ __align__(16) short lds[4][TILE * BK];   // [0]=shared, [2],[3]=per-group
  int nwg = (int)gridDim.x;                           // = 18 * RT
  int RT = p.SG / TILE;
  int l = xcd_swz((int)blockIdx.x, nwg);
  int tid = (int)threadIdx.x;
  int grp = tid >> 8, gt = tid & 255;
  int lane = gt & 63, w = gt >> 6;
  int lr = lane & 15, lk = lane >> 4, wm = w >> 1, wn = w & 1;
  f32x4 acc[4][4]; zero_acc(acc);
  int nvt = 12 * RT;                                  // non-vt pair-blocks
  if (l < nvt) {
    // non-vt: C = Z @ W^T + b. zp 0 -> (z0,z3) share Zg; zp 1 -> (z1,z2) share Zl.
    int zp = l / (6 * RT), t = l % (6 * RT);
    int r0 = (t / 6) * TILE, c0 = (t % 6) * TILE;
    int z = zp == 0 ? (grp ? 3 : 0) : (grp ? 2 : 1);
    const unsigned short* Asrc = p.A[z];              // same for both groups
    const unsigned short* Bsrc = p.B[z];              // per-group weight
    for (int kt = 0; kt < 768 / BK; ++kt) {
      __syncthreads();
      stage_tile512(Asrc, 768, r0, kt * BK, lds[0], tid);
      stage_tile(Bsrc, 768, c0, kt * BK, lds[2 + grp], gt);
      __syncthreads();
      compute_tile(lds[0], lds[2 + grp], acc, lr, lk, wm, wn);
    }
    gemm_epilogue<true, true, false>(acc, p.dst[z], 768, r0, c0, p.bias[z], 1.f, gt);
  } else {
    // vt: V^T = Wv @ Z^T + b(row). Both groups share the Z col-panel (B).
    int lv = l - nvt;                                 // [0, 6*RT)
    int z = 4 + lv / (3 * RT), t = lv % (3 * RT);
    int r0 = ((t % 3) * 2 + grp) * TILE, c0 = (t / 3) * TILE;
    const unsigned short* Asrc = p.A[z];              // per-group rows of Wv
    const unsigned short* Bsrc = p.B[z];              // shared Z panel
    for (int kt = 0; kt < 768 / BK; ++kt) {
      __syncthreads();
      stage_tile512(Bsrc, 768, c0, kt * BK, lds[0], tid);
      stage_tile(Asrc, 768, r0, kt * BK, lds[2 + grp], gt);
      __syncthreads();
      compute_tile(lds[2 + grp], lds[0], acc, lr, lk, wm, wn);
    }
    gemm_epilogue<true, false, true>(acc, p.dst[z], p.SG, r0, c0, p.bias[z], 1.f, gt);
  }
}

// E[z] = exp(Q_gi @ K_gi^T * alpha)  (NO max subtraction: S*alpha ~ N(0,0.33),
// max ~1.8, exp<=12 -- f32 overflows at 88, so max-sub is unnecessary here).
// Row sums l[z][row] via shfl-reduce + atomicAdd; k_pv divides by l, making
// E@V/l == softmax(S)@V exactly.
// R27: SHARED-Q blocks: Q staged ONCE by all 512 threads into lds[0];
// per-group K into lds[2+grp]. Es overlay: grp0 -> lds[0..1], grp1 -> lds[2..3].
__global__ __launch_bounds__(512) void k_scores(const unsigned short* Qg, const unsigned short* Kl,
                                                const unsigned short* Ql, const unsigned short* Kg,
                                                unsigned short* S, float* lsum,
                                                float alpha, int G) {
  __shared__ __align__(16) short lds[4][TILE * BK];   // [0]=Q shared; [2],[3]=per-group K
  int nwg = (int)(gridDim.x * gridDim.y * gridDim.z);
  int h = (int)blockIdx.x + (int)gridDim.x * ((int)blockIdx.y + (int)gridDim.y * (int)blockIdx.z);
  int l = xcd_swz(h, nwg);
  int xp = l & 7, y = (l >> 3) & 15, z = l >> 7;     // gridDim = (8, 16, 2G)
  int tid = (int)threadIdx.x;
  int grp = tid >> 8;    // 0 or 1
  int gt  = tid & 255;
  int x = xp * 2 + grp;
  int dir = (z >= G) ? 1 : 0, gi = z - dir * G;
  const unsigned short* Q = (dir ? Ql : Qg) + (size_t)gi * 2048 * 768;
  const unsigned short* K = (dir ? Kg : Kl) + (size_t)gi * 2048 * 768;
  unsigned short* C = S + (size_t)z * 2048 * 2048;
  float* lrow = lsum + (size_t)z * 2048;
  int r0 = y * TILE, c0 = x * TILE;
  int lane = gt & 63, w = gt >> 6;
  int lr = lane & 15, lk = lane >> 4, wm = w >> 1, wn = w & 1;
  f32x4 acc[4][4]; zero_acc(acc);
  // shared-Q K-loop: Q staged once per block, K per group; lockstep barriers
  for (int kt = 0; kt < 768 / BK; ++kt) {
    __syncthreads();
    stage_tile512(Q, 768, r0, kt * BK, lds[0], tid);
    stage_tile(K, 768, c0, kt * BK, lds[2 + grp], gt);
    __syncthreads();
    compute_tile(lds[0], lds[2 + grp], acc, lr, lk, wm, wn);
  }
  // exp + row-sum, staging E into this group's swizzled LDS region (R15 store)
  __syncthreads();                       // all groups done reading staging
  short* Es = grp ? lds[2] : lds[0];     // 32KB contiguous per group
#pragma unroll
  for (int i = 0; i < 4; ++i) {
    float rs[4] = { 0.f, 0.f, 0.f, 0.f };
#pragma unroll
    for (int j = 0; j < 4; ++j) {
      int lcol = wn * 64 + j * 16 + lr;
#pragma unroll
      for (int r = 0; r < 4; ++r) {
        int lrw = wm * 64 + i * 16 + lk * 4 + r;
        unsigned short eb = f2bf(__expf(acc[i][j][r] * alpha));
        // XOR maps the 4 rows of a wave-write to 4 distinct 16-col blocks ->
        // 64 lanes cover all 32 banks (2-way max = free, m136)
        Es[lrw * TILE + (lcol ^ ((lrw & 7) << 4))] = (short)eb;
        rs[r] += bf2f(eb);               // sum the ROUNDED value PV consumes
      }
    }
#pragma unroll
    for (int r = 0; r < 4; ++r) {
      float v = rs[r];
      v += __shfl_xor(v, 1); v += __shfl_xor(v, 2);
      v += __shfl_xor(v, 4); v += __shfl_xor(v, 8);
      if (lr == 0) atomicAdd(&lrow[r0 + wm * 64 + i * 16 + lk * 4 + r], v);
    }
  }
  __syncthreads();
  // coalesced write-back: 8 x 16B chunks/thread; 16 lanes cover one 256B row
#pragma unroll
  for (int c = 0; c < 8; ++c) {
    int id = c * 256 + gt;
    int lrw = id >> 4, cc = id & 15;     // row, 16B-chunk within row
    uint4 v = *(const uint4*)(Es + lrw * TILE + ((cc * 8) ^ ((lrw & 7) << 4)));
    *(uint4*)(C + (size_t)(r0 + lrw) * 2048 + c0 + cc * 8) = v;
  }
}

// Zf[gi] = (E0 @ Vl)/l0 + (E1 @ Vg)/l1. Split-direction block (R12):
// 512 threads = 2 groups x 4 waves; group g computes E_g @ V_g, scales by
// 1/l_g, then LDS handoff + add.
// R23: LDS 64KB (single-buffer loop per group; f32 reduction buffer OVERLAYS
// staging after a barrier). All blocks co-reside at 2/CU -> no dispatch tail.
__global__ __launch_bounds__(512) void k_pv(const unsigned short* S, const unsigned short* VlT,
                                            const unsigned short* VgT, const float* lsum,
                                            unsigned short* Zf, int G, int SG) {
  __shared__ __align__(16) short lds[4][TILE * BK];   // 4 x 16KB = 64KB
  int nwg = (int)(gridDim.x * gridDim.y * gridDim.z);
  int h = (int)blockIdx.x + (int)gridDim.x * ((int)blockIdx.y + (int)gridDim.y * (int)blockIdx.z);
  int l = xcd_swz(h, nwg);
  int x = l % 6, t2 = l / 6;
  int y = t2 & 15, z = t2 >> 4;        // z in [0,G)
  int r0 = y * TILE, c0 = x * TILE;
  int grp = (int)threadIdx.x >> 8;     // 0 or 1
  int gt  = (int)threadIdx.x & 255;
  f32x4 acc[4][4]; zero_acc(acc);
  GemmSrc s;
  if (grp == 0) s = { S + (size_t)z * 2048 * 2048,       2048, VlT + (size_t)z * 2048, SG, 2048 / BK };
  else          s = { S + (size_t)(G + z) * 2048 * 2048, 2048, VgT + (size_t)z * 2048, SG, 2048 / BK };
  // lockstep: both groups run identical 32-step loops -> barrier counts match
  gemm_accum<1>(&s, acc, lds[grp * 2], lds[grp * 2 + 1], gt, r0, c0);
  int lane = gt & 63, w = gt >> 6;
  int lr = lane & 15, lk = lane >> 4, wm = w >> 1, wn = w & 1;
  // scale this group's partial by its own softmax denominator
  const float* lb = lsum + (size_t)(grp ? (G + z) : z) * 2048;
  float linv[4][4];
#pragma unroll
  for (int i = 0; i < 4; ++i)
#pragma unroll
    for (int r = 0; r < 4; ++r)
      linv[i][r] = 1.0f / lb[r0 + wm * 64 + i * 16 + lk * 4 + r];
#pragma unroll
  for (int i = 0; i < 4; ++i)
#pragma unroll
    for (int j = 0; j < 4; ++j)
#pragma unroll
      for (int r = 0; r < 4; ++r)
        acc[i][j][r] *= linv[i][r];
  float* red = (float*)lds;            // overlays staging (64KB = 128x128 f32)
  __syncthreads();                     // all reads of staging LDS complete
  if (grp == 1) {
#pragma unroll
    for (int i = 0; i < 4; ++i)
#pragma unroll
      for (int j = 0; j < 4; ++j)
#pragma unroll
        for (int r = 0; r < 4; ++r) {
          int row = wm * 64 + i * 16 + lk * 4 + r;
          int col = wn * 64 + j * 16 + lr;
          red[row * 128 + col] = acc[i][j][r];
        }
  }
  __syncthreads();
  if (grp == 0) {
#pragma unroll
    for (int i = 0; i < 4; ++i)
#pragma unroll
      for (int j = 0; j < 4; ++j)
#pragma unroll
        for (int r = 0; r < 4; ++r) {
          int row = wm * 64 + i * 16 + lk * 4 + r;
          int col = wn * 64 + j * 16 + lr;
          acc[i][j][r] += red[row * 128 + col];
        }
    gemm_epilogue<true, false, false>(acc, Zf + (size_t)z * 2048 * 768, 768, r0, c0,
                                      nullptr, 1.f, gt);
  }
}

// out_grp = Zf_grp @ Wf^T + bf (fp32 out) : M=SG, N=768, K=768.
// Flat grid + XCD swizzle + paired staging (R18 win). Stays 256-thread:
// R28 measured the 512-thread shared-A variant WORSE (192 blocks < 256 CUs).
__global__ __launch_bounds__(NT) void k_final(const unsigned short* Zf, const unsigned short* Wf,
                                              const float* bias, float* out) {
  __shared__ __align__(16) short sbuf[4 * TILE * BK];   // 64KB
  int nwg = (int)gridDim.x;
  int l = xcd_swz((int)blockIdx.x, nwg);
  int r0 = (l / 6) * TILE, c0 = (l % 6) * TILE;
  f32x4 acc[4][4]; zero_acc(acc);
  gemm_accum_pair(Zf, 768, Wf, 768, 768 / BK, acc,
                  sbuf, sbuf + TILE * BK, sbuf + 2 * TILE * BK, sbuf + 3 * TILE * BK,
                  threadIdx.x, r0, c0);
  gemm_epilogue<false, true, false>(acc, out, 768, r0, c0, bias, 1.f, threadIdx.x);
}

// ---------------- launch ----------------

extern "C" void kernel_launch(void* const* d_in, const int* in_sizes, int n_in,
                              void* d_out, int out_size, void* d_ws, size_t ws_size,
                              hipStream_t stream) {
  const int B = 8, S = 2048, D = 768;

  const float* Zg  = (const float*)d_in[0];
  const float* Zl  = (const float*)d_in[1];
  const float* bqg = (const float*)d_in[3];
  const float* bkl = (const float*)d_in[5];
  const float* bvl = (const float*)d_in[7];
  const float* bql = (const float*)d_in[9];
  const float* bkg = (const float*)d_in[11];
  const float* bvg = (const float*)d_in[13];
  const float* bf  = (const float*)d_in[15];

  // need(G) = 7 weights + 6 group bufs + lsum + max(Zbf pair, 2G score slices)
  // + 1MB. G=8: 295MB, G=4: 152, G=2: 80.6. R18 ledger implies G=4 engages.
  auto needG = [&](int G) -> size_t {
    size_t zrow = (size_t)G * S * D * 2;
    size_t sb = (size_t)2 * G * S * S * 2;
    size_t zbf = 2 * zrow;
    return 7 * ((size_t)D * D * 2) + 6 * zrow + (size_t)2 * G * S * 4
         + (sb > zbf ? sb : zbf) + (1u << 20);
  };
  int G = 1;
  if      (ws_size >= needG(8)) G = 8;
  else if (ws_size >= needG(4)) G = 4;
  else if (ws_size >= needG(2)) G = 2;
  const int SG = G * S;

  char* w = (char*)d_ws;
  size_t off = 0;
  auto alloc = [&](size_t bytes) -> char* {
    char* p = w + off; off += (bytes + 255) & ~(size_t)255; return p;
  };
  const size_t ZROW = (size_t)SG * D * 2;
  unsigned short* Wbf[7];
  for (int i = 0; i < 7; ++i) Wbf[i] = (unsigned short*)alloc((size_t)D * D * 2);
  unsigned short* QgZf  = (unsigned short*)alloc(ZROW);  // Qg, then reused as Zf
  unsigned short* Kl    = (unsigned short*)alloc(ZROW);
  unsigned short* Ql    = (unsigned short*)alloc(ZROW);
  unsigned short* Kg    = (unsigned short*)alloc(ZROW);
  unsigned short* VlT   = (unsigned short*)alloc(ZROW);  // [768][SG]
  unsigned short* VgT   = (unsigned short*)alloc(ZROW);  // [768][SG]
  float* lsum = (float*)alloc((size_t)2 * G * S * 4);    // [2G][2048] row sums
  // Overlay: Zg_bf/Zl_bf (convert->projall) share space with Sb (scores->pv)
  size_t ov = off;
  unsigned short* Zg_bf = (unsigned short*)alloc(ZROW);
  unsigned short* Zl_bf = (unsigned short*)alloc(ZROW);
  unsigned short* Sb    = (unsigned short*)(w + ov);

  // weights fp32 -> bf16 (once). Order: Wqg Wkl Wvl Wql Wkg Wvg Wf.
  ConvW cw;
  cw.src[0] = (const float*)d_in[2];  cw.src[1] = (const float*)d_in[4];
  cw.src[2] = (const float*)d_in[6];  cw.src[3] = (const float*)d_in[8];
  cw.src[4] = (const float*)d_in[10]; cw.src[5] = (const float*)d_in[12];
  cw.src[6] = (const float*)d_in[14];
  for (int i = 0; i < 7; ++i) cw.dst[i] = Wbf[i];
  k_convert_w<<<dim3(576, 7), NT, 0, stream>>>(cw);

  // merged projections (4 proj + 2 projVT)
  ProjAllArgs pj;
  pj.A[0] = Zg_bf;  pj.B[0] = Wbf[0]; pj.bias[0] = bqg; pj.dst[0] = QgZf;
  pj.A[1] = Zl_bf;  pj.B[1] = Wbf[1]; pj.bias[1] = bkl; pj.dst[1] = Kl;
  pj.A[2] = Zl_bf;  pj.B[2] = Wbf[3]; pj.bias[2] = bql; pj.dst[2] = Ql;
  pj.A[3] = Zg_bf;  pj.B[3] = Wbf[4]; pj.bias[3] = bkg; pj.dst[3] = Kg;
  pj.A[4] = Wbf[2]; pj.B[4] = Zl_bf;  pj.bias[4] = bvl; pj.dst[4] = VlT;
  pj.A[5] = Wbf[5]; pj.B[5] = Zg_bf;  pj.bias[5] = bvg; pj.dst[5] = VgT;
  pj.SG = SG;

  float alpha = 1.0f / sqrtf(768.0f);
  const int nZ = SG * D;
  const int nL = 2 * G * S;   // lsum element count
  const int RT = SG / TILE;

  for (int b0 = 0; b0 < B; b0 += G) {
    k_convert_z<<<dim3(1024, 2), NT, 0, stream>>>(Zg, Zl, Zg_bf, Zl_bf, lsum, nL,
                                                  (long long)b0 * S * D, nZ);
    k_projall<<<dim3(18 * RT), 512, 0, stream>>>(pj);
    k_scores<<<dim3(8, 16, 2 * G), 512, 0, stream>>>(QgZf, Kl, Ql, Kg, Sb, lsum, alpha, G);
    k_pv<<<dim3(6, 16, G), 512, 0, stream>>>(Sb, VlT, VgT, lsum, QgZf, G, SG);
    k_final<<<dim3(6 * (SG / TILE)), NT, 0, stream>>>(QgZf, Wbf[6], bf,
                                                      (float*)d_out + (size_t)b0 * S * D);
  }
}